// Round 7
// baseline (730.660 us; speedup 1.0000x reference)
//
#include <hip/hip_runtime.h>

#define NV 200000
#define NCH 391    // chunks of 512 voxels
#define PCAP 56    // pair capacity per (tap, chunk); mean ~14
#define CG 3125    // center blocks (64 rows each)
#define PN 3516    // partial rows per tensor: CG center + NCH off

typedef __attribute__((ext_vector_type(8))) short sh8;
typedef __attribute__((ext_vector_type(4))) float f32x4;
typedef __attribute__((ext_vector_type(2))) unsigned int u32x2;

__device__ inline unsigned short f2bf(float f) {
  unsigned int u = __builtin_bit_cast(unsigned int, f);
  u += 0x7FFFu + ((u >> 16) & 1u);
  return (unsigned short)(u >> 16);
}
__device__ inline float bf2f(unsigned short h) {
  unsigned int u = ((unsigned int)h) << 16;
  return __builtin_bit_cast(float, u);
}
__device__ inline float lrelu(float v) { return v >= 0.f ? v : 0.01f * v; }

// ---------------------------------------------------------------------------
// prep: [blocks 0..35] weight transpose W[k][c][d]f32 -> Wt[k][d][c]bf16 via
//       LDS tile (coalesced both sides; avoids 32x strided-read overfetch).
//       [blocks 36..] pair-list build per (slot, 512-voxel chunk), ballot
//       compaction (deterministic, no atomics, sorted by voxel).
// ---------------------------------------------------------------------------
__global__ __launch_bounds__(256) void prep_k(
    const float* __restrict__ W1, const float* __restrict__ W12,
    const float* __restrict__ W2, const float* __restrict__ W3,
    unsigned short* __restrict__ T1, unsigned short* __restrict__ T12,
    unsigned short* __restrict__ T2, unsigned short* __restrict__ T3,
    const int* __restrict__ nbr31, const int* __restrict__ nbr13,
    int2* __restrict__ pairs, int* __restrict__ cc) {
  __shared__ unsigned short lt[64 * 130];
  __shared__ int base_s[4];
  __shared__ int run;
  int bx = blockIdx.x;
  const int tid = threadIdx.x;
  if (bx < 36) {
    const float* src;
    unsigned short* dst;
    int cin, k;
    if (bx < 9) { src = W1; dst = T1; cin = 64; k = bx; }
    else if (bx < 18) { src = W2; dst = T2; cin = 64; k = bx - 9; }
    else if (bx < 27) { src = W12; dst = T12; cin = 128; k = bx - 18; }
    else { src = W3; dst = T3; cin = 128; k = bx - 27; }
    src += (size_t)k * cin * 128;
    dst += (size_t)k * 128 * cin;
    const int cmask = cin - 1;
    const int csh = (cin == 64) ? 6 : 7;
    for (int h = 0; h < 2; ++h) {  // d-halves [h*64, h*64+64)
      if (h) __syncthreads();
      const int tot = cin * 64;
      for (int e = tid; e < tot; e += 256) {
        const int c = e >> 6, dd = e & 63;
        lt[dd * 130 + c] = f2bf(src[c * 128 + h * 64 + dd]);
      }
      __syncthreads();
      for (int o = tid; o < tot; o += 256) {
        const int dl = o >> csh, c = o & cmask;
        dst[(size_t)(h * 64 + dl) * cin + c] = lt[dl * 130 + c];
      }
    }
    return;
  }
  bx -= 36;
  const int slot = bx / NCH, chunk = bx % NCH;
  const int table = slot >> 3, kk = slot & 7;
  const int k = kk + (kk >= 4);
  const int* nb = (table ? nbr13 : nbr31) + (size_t)k * NV;
  const int lane = tid & 63, wv = tid >> 6;
  if (tid == 0) run = 0;
  __syncthreads();
  int2* pw = pairs + (size_t)(slot * NCH + chunk) * PCAP;
#pragma unroll
  for (int i = 0; i < 2; ++i) {
    const int n = chunk * 512 + i * 256 + tid;
    const int val = (n < NV) ? nb[n] : NV;
    const bool valid = (val != NV);
    const unsigned long long m = __ballot(valid);
    const int loff = __popcll(m & ((1ull << lane) - 1ull));
    if (lane == 0) base_s[wv] = __popcll(m);
    __syncthreads();
    int wbase = run;
    for (int w = 0; w < wv; ++w) wbase += base_s[w];
    if (valid) {
      const int pos = wbase + loff;
      if (pos < PCAP) {
        int2 pr;
        pr.x = val;
        pr.y = n;
        pw[pos] = pr;
      }
    }
    __syncthreads();
    if (tid == 0) run += base_s[0] + base_s[1] + base_s[2] + base_s[3];
    __syncthreads();
  }
  if (tid == 0) cc[slot * NCH + chunk] = min(run, PCAP);
}

// ---------------------------------------------------------------------------
// Epilogue helpers (shared by center kernels):
//  - stats_reduce: shfl over l15 -> l15==0 lanes hold per-d sums
//  - LDS-staged coalesced store of one 64x128 bf16 tile
// ---------------------------------------------------------------------------
#define STATS_EMIT(ACC, PART)                                                   \
  {                                                                             \
    f32x4 ssum[2], ssq[2];                                                      \
    _Pragma("unroll") for (int mt = 0; mt < 2; ++mt) {                          \
      ssum[mt] = (f32x4){0.f, 0.f, 0.f, 0.f};                                   \
      ssq[mt] = (f32x4){0.f, 0.f, 0.f, 0.f};                                    \
      _Pragma("unroll") for (int nt = 0; nt < 4; ++nt)                          \
          _Pragma("unroll") for (int q = 0; q < 4; ++q) {                       \
        const float f = lrelu(ACC[mt][nt][q]);                                  \
        ssum[mt][q] += f;                                                       \
        ssq[mt][q] += f * f;                                                    \
      }                                                                         \
      _Pragma("unroll") for (int off = 1; off < 16; off <<= 1)                  \
          _Pragma("unroll") for (int q = 0; q < 4; ++q) {                       \
        ssum[mt][q] += __shfl_xor(ssum[mt][q], off);                            \
        ssq[mt][q] += __shfl_xor(ssq[mt][q], off);                              \
      }                                                                         \
      if (l15 == 0) {                                                           \
        const int d0 = (wv * 2 + mt) * 16 + l4 * 4;                             \
        *(f32x4*)(PART + (size_t)blockIdx.x * 256 + d0) = ssum[mt];             \
        *(f32x4*)(PART + (size_t)blockIdx.x * 256 + 128 + d0) = ssq[mt];        \
      }                                                                         \
    }                                                                           \
  }

#define TILE_OUT(ACC, YPTR)                                                     \
  {                                                                             \
    __syncthreads();                                                            \
    _Pragma("unroll") for (int mt = 0; mt < 2; ++mt)                            \
        _Pragma("unroll") for (int nt = 0; nt < 4; ++nt) {                      \
      u32x2 pk;                                                                 \
      pk[0] = (unsigned)f2bf(ACC[mt][nt][0]) |                                  \
              ((unsigned)f2bf(ACC[mt][nt][1]) << 16);                           \
      pk[1] = (unsigned)f2bf(ACC[mt][nt][2]) |                                  \
              ((unsigned)f2bf(ACC[mt][nt][3]) << 16);                           \
      *(u32x2*)(&lds[(nt * 16 + l15) * 136 + (wv * 2 + mt) * 16 + l4 * 4]) = pk;\
    }                                                                           \
    __syncthreads();                                                            \
    _Pragma("unroll") for (int j = 0; j < 4; ++j) {                             \
      const int row = j * 16 + (tid >> 4);                                      \
      const int c16 = tid & 15;                                                 \
      const sh8 v = *(const sh8*)(&lds[row * 136 + c16 * 8]);                   \
      *(sh8*)(YPTR + (size_t)(row0 + row) * 128 + c16 * 8) = v;                 \
    }                                                                           \
  }

// ---------------------------------------------------------------------------
// Fused center GEMM for L0+L2: reads feats f32 directly; emits y1,y2 plus
// per-block lrelu stats partials (PA/PB rows [0, CG)).
// ---------------------------------------------------------------------------
__global__ __launch_bounds__(256) void center2_k(
    const float* __restrict__ X, const unsigned short* __restrict__ W1t,
    const unsigned short* __restrict__ W2t, unsigned short* __restrict__ Y1,
    unsigned short* __restrict__ Y2, float* __restrict__ PA,
    float* __restrict__ PB) {
  constexpr int CIN = 64, CH = 8;
  __shared__ unsigned short lds[64 * 136];
  const int tid = threadIdx.x, lane = tid & 63, wv = tid >> 6;
  const int l15 = lane & 15, l4 = lane >> 4;
  const int row0 = blockIdx.x * 64;
  const int js = tid & 7;
#pragma unroll
  for (int i = 0; i < 2; ++i) {
    const int r = (i * 256 + tid) >> 3;
    const f32x4 a = *(const f32x4*)(X + (size_t)(row0 + r) * CIN + js * 8);
    const f32x4 b = *(const f32x4*)(X + (size_t)(row0 + r) * CIN + js * 8 + 4);
    sh8 o;
#pragma unroll
    for (int j = 0; j < 4; ++j) {
      o[j] = (short)f2bf(a[j]);
      o[4 + j] = (short)f2bf(b[j]);
    }
    *(sh8*)(lds + ((size_t)r * CH + (js ^ (r & 7))) * 8) = o;
  }
  __syncthreads();

  f32x4 acc1[2][4], acc2[2][4];
#pragma unroll
  for (int mt = 0; mt < 2; ++mt)
#pragma unroll
    for (int nt = 0; nt < 4; ++nt) {
      acc1[mt][nt] = (f32x4){0.f, 0.f, 0.f, 0.f};
      acc2[mt][nt] = (f32x4){0.f, 0.f, 0.f, 0.f};
    }
  const unsigned short* W1K = W1t + (size_t)(4 * 128) * CIN;
  const unsigned short* W2K = W2t + (size_t)(4 * 128) * CIN;
#pragma unroll
  for (int s = 0; s < 2; ++s) {
    sh8 aw1[2], aw2[2];
#pragma unroll
    for (int mt = 0; mt < 2; ++mt) {
      const int d = (wv * 2 + mt) * 16 + l15;
      aw1[mt] = *(const sh8*)(W1K + (size_t)d * CIN + s * 32 + l4 * 8);
      aw2[mt] = *(const sh8*)(W2K + (size_t)d * CIN + s * 32 + l4 * 8);
    }
#pragma unroll
    for (int nt = 0; nt < 4; ++nt) {
      const int r = nt * 16 + l15;
      const int j = s * 4 + l4;
      const sh8 bx = *(const sh8*)(lds + ((size_t)r * CH + (j ^ (r & 7))) * 8);
#pragma unroll
      for (int mt = 0; mt < 2; ++mt) {
        acc1[mt][nt] =
            __builtin_amdgcn_mfma_f32_16x16x32_bf16(aw1[mt], bx, acc1[mt][nt], 0, 0, 0);
        acc2[mt][nt] =
            __builtin_amdgcn_mfma_f32_16x16x32_bf16(aw2[mt], bx, acc2[mt][nt], 0, 0, 0);
      }
    }
  }
  STATS_EMIT(acc1, PA)
  STATS_EMIT(acc2, PB)
  TILE_OUT(acc1, Y1)
  __syncthreads();
  TILE_OUT(acc2, Y2)
}

// ---------------------------------------------------------------------------
// Center GEMM, CIN=128, affine+lrelu on input; emits Y + stats partials.
// ---------------------------------------------------------------------------
__global__ __launch_bounds__(256) void c128_k(
    const unsigned short* __restrict__ X, const unsigned short* __restrict__ Wt,
    const float* __restrict__ abp, unsigned short* __restrict__ Y,
    float* __restrict__ PART) {
  constexpr int CIN = 128, CH = 16;
  __shared__ unsigned short lds[64 * 136];
  const int row0 = blockIdx.x * 64;
  const int tid = threadIdx.x, lane = tid & 63, wv = tid >> 6;
  const int l15 = lane & 15, l4 = lane >> 4;
  const int js = tid & 15;
  const f32x4 aL = *(const f32x4*)(abp + js * 8);
  const f32x4 aH = *(const f32x4*)(abp + js * 8 + 4);
  const f32x4 bL = *(const f32x4*)(abp + 128 + js * 8);
  const f32x4 bH = *(const f32x4*)(abp + 128 + js * 8 + 4);
#pragma unroll
  for (int i = 0; i < 4; ++i) {
    const int r = (i * 256 + tid) >> 4;
    const sh8 v = *(const sh8*)(X + (size_t)(row0 + r) * CIN + js * 8);
    sh8 o;
#pragma unroll
    for (int j = 0; j < 4; ++j) {
      o[j] = (short)f2bf(lrelu(bf2f((unsigned short)v[j])) * aL[j] + bL[j]);
      o[4 + j] = (short)f2bf(lrelu(bf2f((unsigned short)v[4 + j])) * aH[j] + bH[j]);
    }
    *(sh8*)(lds + ((size_t)r * CH + (js ^ (r & 7))) * 8) = o;
  }
  __syncthreads();

  f32x4 acc[2][4];
#pragma unroll
  for (int mt = 0; mt < 2; ++mt)
#pragma unroll
    for (int nt = 0; nt < 4; ++nt) acc[mt][nt] = (f32x4){0.f, 0.f, 0.f, 0.f};

  const unsigned short* WtK = Wt + (size_t)(4 * 128) * CIN;
#pragma unroll
  for (int s = 0; s < 4; ++s) {
    sh8 aw[2];
#pragma unroll
    for (int mt = 0; mt < 2; ++mt) {
      const int d = (wv * 2 + mt) * 16 + l15;
      aw[mt] = *(const sh8*)(WtK + (size_t)d * CIN + s * 32 + l4 * 8);
    }
#pragma unroll
    for (int nt = 0; nt < 4; ++nt) {
      const int r = nt * 16 + l15;
      const int j = s * 4 + l4;
      const sh8 bxv = *(const sh8*)(lds + ((size_t)r * CH + (j ^ (r & 7))) * 8);
#pragma unroll
      for (int mt = 0; mt < 2; ++mt)
        acc[mt][nt] =
            __builtin_amdgcn_mfma_f32_16x16x32_bf16(aw[mt], bxv, acc[mt][nt], 0, 0, 0);
    }
  }
  STATS_EMIT(acc, PART)
  TILE_OUT(acc, Y)
}

// ---------------------------------------------------------------------------
// Off-center taps for L0+L2 (input feats f32), atomic-free RMW + delta stats.
// grid = 2 layers * NCH; block owns output rows [chunk*512,+512); loops 8 taps.
// ---------------------------------------------------------------------------
__global__ __launch_bounds__(256) void off64_k(
    const float* __restrict__ X, const unsigned short* __restrict__ T1,
    const unsigned short* __restrict__ T2, const int2* __restrict__ pairs,
    const int* __restrict__ cc, unsigned short* __restrict__ y1,
    unsigned short* __restrict__ y2, float* __restrict__ PA,
    float* __restrict__ PB) {
  constexpr int CIN = 64, CH = 8;
  const int layer = blockIdx.x / NCH, chunk = blockIdx.x % NCH;
  const unsigned short* Wt = layer ? T2 : T1;
  unsigned short* Y = layer ? y2 : y1;
  float* PD = layer ? PB : PA;
  const int* ccl = cc + layer * 8 * NCH;
  const int2* pl = pairs + (size_t)layer * 8 * NCH * PCAP;
  __shared__ unsigned short tile[64 * CIN];
  __shared__ int sin[64], sout[64];
  const int tid = threadIdx.x, lane = tid & 63, wv = tid >> 6;
  const int l15 = lane & 15, l4 = lane >> 4;
  const int js = tid & 7;
  f32x4 ds[2], dq[2];
#pragma unroll
  for (int mt = 0; mt < 2; ++mt) {
    ds[mt] = (f32x4){0.f, 0.f, 0.f, 0.f};
    dq[mt] = (f32x4){0.f, 0.f, 0.f, 0.f};
  }

  for (int kk = 0; kk < 8; ++kk) {
    const int n0 = ccl[kk * NCH + chunk];
    if (n0 == 0) continue;
    const int k = kk + (kk >= 4);
    const unsigned short* WtK = Wt + (size_t)k * 128 * CIN;
    __syncthreads();
    if (tid < 64) {
      int2 pr;
      if (tid < n0) pr = pl[(size_t)(kk * NCH + chunk) * PCAP + tid];
      else { pr.x = NV; pr.y = NV; }
      sin[tid] = pr.x;
      sout[tid] = pr.y;
    }
    __syncthreads();
#pragma unroll
    for (int i = 0; i < 2; ++i) {
      const int r = (i * 256 + tid) >> 3;
      const int in = sin[r];
      sh8 o = (sh8){0, 0, 0, 0, 0, 0, 0, 0};
      if (in != NV) {
        const f32x4 a = *(const f32x4*)(X + (size_t)in * CIN + js * 8);
        const f32x4 b = *(const f32x4*)(X + (size_t)in * CIN + js * 8 + 4);
#pragma unroll
        for (int j = 0; j < 4; ++j) {
          o[j] = (short)f2bf(a[j]);
          o[4 + j] = (short)f2bf(b[j]);
        }
      }
      *(sh8*)(tile + ((size_t)r * CH + (js ^ (r & 7))) * 8) = o;
    }
    __syncthreads();

    f32x4 acc[2][4];
#pragma unroll
    for (int mt = 0; mt < 2; ++mt)
#pragma unroll
      for (int nt = 0; nt < 4; ++nt) acc[mt][nt] = (f32x4){0.f, 0.f, 0.f, 0.f};
#pragma unroll
    for (int s = 0; s < 2; ++s) {
      sh8 aw[2];
#pragma unroll
      for (int mt = 0; mt < 2; ++mt) {
        const int d = (wv * 2 + mt) * 16 + l15;
        aw[mt] = *(const sh8*)(WtK + (size_t)d * CIN + s * 32 + l4 * 8);
      }
#pragma unroll
      for (int nt = 0; nt < 4; ++nt) {
        const int r = nt * 16 + l15;
        const int j = s * 4 + l4;
        const sh8 bxv = *(const sh8*)(tile + ((size_t)r * CH + (j ^ (r & 7))) * 8);
#pragma unroll
        for (int mt = 0; mt < 2; ++mt)
          acc[mt][nt] =
              __builtin_amdgcn_mfma_f32_16x16x32_bf16(aw[mt], bxv, acc[mt][nt], 0, 0, 0);
      }
    }
#pragma unroll
    for (int mt = 0; mt < 2; ++mt)
#pragma unroll
      for (int nt = 0; nt < 4; ++nt) {
        const int out = sout[nt * 16 + l15];
        if (out == NV) continue;
        const int d0 = (wv * 2 + mt) * 16 + l4 * 4;
        unsigned short* p = Y + (size_t)out * 128 + d0;
        const u32x2 old = *(const u32x2*)p;
        u32x2 nw;
        float of[4], sf[4];
        of[0] = bf2f((unsigned short)(old[0] & 0xffff));
        of[1] = bf2f((unsigned short)(old[0] >> 16));
        of[2] = bf2f((unsigned short)(old[1] & 0xffff));
        of[3] = bf2f((unsigned short)(old[1] >> 16));
#pragma unroll
        for (int q = 0; q < 4; ++q) {
          sf[q] = of[q] + acc[mt][nt][q];
          const float ln = lrelu(sf[q]), lo = lrelu(of[q]);
          ds[mt][q] += ln - lo;
          dq[mt][q] += ln * ln - lo * lo;
        }
        nw[0] = (unsigned)f2bf(sf[0]) | ((unsigned)f2bf(sf[1]) << 16);
        nw[1] = (unsigned)f2bf(sf[2]) | ((unsigned)f2bf(sf[3]) << 16);
        *(u32x2*)p = nw;
      }
  }
  // reduce deltas over l15 group, write PD row CG+chunk
#pragma unroll
  for (int mt = 0; mt < 2; ++mt) {
#pragma unroll
    for (int off = 1; off < 16; off <<= 1)
#pragma unroll
      for (int q = 0; q < 4; ++q) {
        ds[mt][q] += __shfl_xor(ds[mt][q], off);
        dq[mt][q] += __shfl_xor(dq[mt][q], off);
      }
    if (l15 == 0) {
      const int d0 = (wv * 2 + mt) * 16 + l4 * 4;
      *(f32x4*)(PD + (size_t)(CG + chunk) * 256 + d0) = ds[mt];
      *(f32x4*)(PD + (size_t)(CG + chunk) * 256 + 128 + d0) = dq[mt];
    }
  }
}

// ---------------------------------------------------------------------------
// Off-center taps, CIN=128, one table, RMW + delta stats. grid = NCH.
// ---------------------------------------------------------------------------
__global__ __launch_bounds__(256) void off128_k(
    const unsigned short* __restrict__ X, const unsigned short* __restrict__ Wt,
    const int2* __restrict__ pairs_t, const int* __restrict__ cc_t,
    const float* __restrict__ abp, unsigned short* __restrict__ Y,
    float* __restrict__ PD) {
  constexpr int CIN = 128, CH = 16;
  const int chunk = blockIdx.x;
  __shared__ unsigned short tile[64 * CIN];
  __shared__ int sin[64], sout[64];
  const int tid = threadIdx.x, lane = tid & 63, wv = tid >> 6;
  const int l15 = lane & 15, l4 = lane >> 4;
  const int js = tid & 15;
  const f32x4 aL = *(const f32x4*)(abp + js * 8);
  const f32x4 aH = *(const f32x4*)(abp + js * 8 + 4);
  const f32x4 bL = *(const f32x4*)(abp + 128 + js * 8);
  const f32x4 bH = *(const f32x4*)(abp + 128 + js * 8 + 4);
  f32x4 ds[2], dq[2];
#pragma unroll
  for (int mt = 0; mt < 2; ++mt) {
    ds[mt] = (f32x4){0.f, 0.f, 0.f, 0.f};
    dq[mt] = (f32x4){0.f, 0.f, 0.f, 0.f};
  }

  for (int kk = 0; kk < 8; ++kk) {
    const int n0 = cc_t[kk * NCH + chunk];
    if (n0 == 0) continue;
    const int k = kk + (kk >= 4);
    const unsigned short* WtK = Wt + (size_t)k * 128 * CIN;
    __syncthreads();
    if (tid < 64) {
      int2 pr;
      if (tid < n0) pr = pairs_t[(size_t)(kk * NCH + chunk) * PCAP + tid];
      else { pr.x = NV; pr.y = NV; }
      sin[tid] = pr.x;
      sout[tid] = pr.y;
    }
    __syncthreads();
#pragma unroll
    for (int i = 0; i < 4; ++i) {
      const int r = (i * 256 + tid) >> 4;
      const int in = sin[r];
      sh8 o = (sh8){0, 0, 0, 0, 0, 0, 0, 0};
      if (in != NV) {
        const sh8 v = *(const sh8*)(X + (size_t)in * CIN + js * 8);
#pragma unroll
        for (int j = 0; j < 4; ++j) {
          o[j] = (short)f2bf(lrelu(bf2f((unsigned short)v[j])) * aL[j] + bL[j]);
          o[4 + j] = (short)f2bf(lrelu(bf2f((unsigned short)v[4 + j])) * aH[j] + bH[j]);
        }
      }
      *(sh8*)(tile + ((size_t)r * CH + (js ^ (r & 7))) * 8) = o;
    }
    __syncthreads();

    f32x4 acc[2][4];
#pragma unroll
    for (int mt = 0; mt < 2; ++mt)
#pragma unroll
      for (int nt = 0; nt < 4; ++nt) acc[mt][nt] = (f32x4){0.f, 0.f, 0.f, 0.f};
#pragma unroll
    for (int s = 0; s < 4; ++s) {
      sh8 aw[2];
#pragma unroll
      for (int mt = 0; mt < 2; ++mt) {
        const int d = (wv * 2 + mt) * 16 + l15;
        aw[mt] = *(const sh8*)(WtK + (size_t)d * CIN + s * 32 + l4 * 8);
      }
#pragma unroll
      for (int nt = 0; nt < 4; ++nt) {
        const int r = nt * 16 + l15;
        const int j = s * 4 + l4;
        const sh8 bxv = *(const sh8*)(tile + ((size_t)r * CH + (j ^ (r & 7))) * 8);
#pragma unroll
        for (int mt = 0; mt < 2; ++mt)
          acc[mt][nt] =
              __builtin_amdgcn_mfma_f32_16x16x32_bf16(aw[mt], bxv, acc[mt][nt], 0, 0, 0);
      }
    }
#pragma unroll
    for (int mt = 0; mt < 2; ++mt)
#pragma unroll
      for (int nt = 0; nt < 4; ++nt) {
        const int out = sout[nt * 16 + l15];
        if (out == NV) continue;
        const int d0 = (wv * 2 + mt) * 16 + l4 * 4;
        unsigned short* p = Y + (size_t)out * 128 + d0;
        const u32x2 old = *(const u32x2*)p;
        u32x2 nw;
        float of[4], sf[4];
        of[0] = bf2f((unsigned short)(old[0] & 0xffff));
        of[1] = bf2f((unsigned short)(old[0] >> 16));
        of[2] = bf2f((unsigned short)(old[1] & 0xffff));
        of[3] = bf2f((unsigned short)(old[1] >> 16));
#pragma unroll
        for (int q = 0; q < 4; ++q) {
          sf[q] = of[q] + acc[mt][nt][q];
          const float ln = lrelu(sf[q]), lo = lrelu(of[q]);
          ds[mt][q] += ln - lo;
          dq[mt][q] += ln * ln - lo * lo;
        }
        nw[0] = (unsigned)f2bf(sf[0]) | ((unsigned)f2bf(sf[1]) << 16);
        nw[1] = (unsigned)f2bf(sf[2]) | ((unsigned)f2bf(sf[3]) << 16);
        *(u32x2*)p = nw;
      }
  }
#pragma unroll
  for (int mt = 0; mt < 2; ++mt) {
#pragma unroll
    for (int off = 1; off < 16; off <<= 1)
#pragma unroll
      for (int q = 0; q < 4; ++q) {
        ds[mt][q] += __shfl_xor(ds[mt][q], off);
        dq[mt][q] += __shfl_xor(dq[mt][q], off);
      }
    if (l15 == 0) {
      const int d0 = (wv * 2 + mt) * 16 + l4 * 4;
      *(f32x4*)(PD + (size_t)(CG + chunk) * 256 + d0) = ds[mt];
      *(f32x4*)(PD + (size_t)(CG + chunk) * 256 + 128 + d0) = dq[mt];
    }
  }
}

// ---------------------------------------------------------------------------
// Reduce PN partial rows -> per-channel scale/bias. 2 blocks x 1024 threads.
// ---------------------------------------------------------------------------
__global__ __launch_bounds__(1024) void fin2_k(
    const float* __restrict__ PA, const float* __restrict__ gA,
    const float* __restrict__ btA, float* __restrict__ abA,
    const float* __restrict__ PB, const float* __restrict__ gB,
    const float* __restrict__ btB, float* __restrict__ abB) {
  const float* P = blockIdx.x ? PB : PA;
  const float* g = blockIdx.x ? gB : gA;
  const float* bt = blockIdx.x ? btB : btA;
  float* abo = blockIdx.x ? abB : abA;
  __shared__ float S[1024];
  const int t = threadIdx.x;
  const int c = t & 255, grp = t >> 8;
  float s = 0.f;
  for (int b = grp; b < PN; b += 4) s += P[(size_t)b * 256 + c];
  S[t] = s;
  __syncthreads();
  if (t < 256) S[t] = S[t] + S[256 + t] + S[512 + t] + S[768 + t];
  __syncthreads();
  if (t < 128) {
    const float m = S[t] * (1.0f / (float)NV);
    const float v = S[128 + t] * (1.0f / (float)NV) - m * m;
    const float a = g[t] * rsqrtf(v + 1e-5f);
    abo[t] = a;
    abo[128 + t] = bt[t] - m * a;
  }
}

// ---------------------------------------------------------------------------
// out = bn2(lrelu(y3)) + bn0_2(lrelu(ysc))   (f32 output)
// ---------------------------------------------------------------------------
__global__ __launch_bounds__(256) void final_k(const unsigned short* __restrict__ y3,
                                               const unsigned short* __restrict__ ysc,
                                               const float* __restrict__ ab3,
                                               const float* __restrict__ ab1,
                                               float* __restrict__ out) {
  const long i = (long)blockIdx.x * 256 + threadIdx.x;
  if (i >= (long)NV * 16) return;
  const long base = i * 8;
  const int c0 = (int)(base & 127);
  const sh8 v3 = *(const sh8*)(y3 + base);
  const sh8 vs = *(const sh8*)(ysc + base);
  const f32x4 a3L = *(const f32x4*)(ab3 + c0);
  const f32x4 a3H = *(const f32x4*)(ab3 + c0 + 4);
  const f32x4 b3L = *(const f32x4*)(ab3 + 128 + c0);
  const f32x4 b3H = *(const f32x4*)(ab3 + 128 + c0 + 4);
  const f32x4 a1L = *(const f32x4*)(ab1 + c0);
  const f32x4 a1H = *(const f32x4*)(ab1 + c0 + 4);
  const f32x4 b1L = *(const f32x4*)(ab1 + 128 + c0);
  const f32x4 b1H = *(const f32x4*)(ab1 + 128 + c0 + 4);
  f32x4 oL, oH;
#pragma unroll
  for (int j = 0; j < 4; ++j) {
    oL[j] = a3L[j] * lrelu(bf2f((unsigned short)v3[j])) + b3L[j] +
            a1L[j] * lrelu(bf2f((unsigned short)vs[j])) + b1L[j];
    oH[j] = a3H[j] * lrelu(bf2f((unsigned short)v3[4 + j])) + b3H[j] +
            a1H[j] * lrelu(bf2f((unsigned short)vs[4 + j])) + b1H[j];
  }
  *(f32x4*)(out + base) = oL;
  *(f32x4*)(out + base + 4) = oH;
}

// ---------------------------------------------------------------------------
extern "C" void kernel_launch(void* const* d_in, const int* in_sizes, int n_in,
                              void* d_out, int out_size, void* d_ws, size_t ws_size,
                              hipStream_t stream) {
  const float* feats = (const float*)d_in[0];
  const float* W1 = (const float*)d_in[1];
  const float* W12 = (const float*)d_in[2];
  const float* W2 = (const float*)d_in[3];
  const float* W3 = (const float*)d_in[4];
  const float* g0 = (const float*)d_in[5];
  const float* b0 = (const float*)d_in[6];
  const float* g02 = (const float*)d_in[7];
  const float* b02 = (const float*)d_in[8];
  const float* g1 = (const float*)d_in[9];
  const float* b1 = (const float*)d_in[10];
  const float* g2 = (const float*)d_in[11];
  const float* b2 = (const float*)d_in[12];
  const int* nbr31 = (const int*)d_in[13];
  const int* nbr13 = (const int*)d_in[14];
  float* out = (float*)d_out;

  char* ws = (char*)d_ws;
  size_t off = 0;
  auto alloc = [&](size_t bytes) {
    char* p = ws + off;
    off = (off + bytes + 255) & ~(size_t)255;
    return p;
  };

  unsigned short* T1 = (unsigned short*)alloc((size_t)9 * 128 * 64 * 2);
  unsigned short* T2 = (unsigned short*)alloc((size_t)9 * 128 * 64 * 2);
  unsigned short* T12 = (unsigned short*)alloc((size_t)9 * 128 * 128 * 2);
  unsigned short* T3 = (unsigned short*)alloc((size_t)9 * 128 * 128 * 2);
  unsigned short* y1 = (unsigned short*)alloc((size_t)NV * 128 * 2);
  unsigned short* ysc = (unsigned short*)alloc((size_t)NV * 128 * 2);
  unsigned short* y2 = (unsigned short*)alloc((size_t)NV * 128 * 2);
  float* PA = (float*)alloc((size_t)PN * 256 * 4);
  float* PB = (float*)alloc((size_t)PN * 256 * 4);
  float* ab = (float*)alloc(1024 * 4);
  int* cc = (int*)alloc((size_t)16 * NCH * 4);
  int2* pairs = (int2*)alloc((size_t)16 * NCH * PCAP * 8);
  unsigned short* y3 = y1;  // y1 reused as y3 only after all y1 readers drain

  const int2* pairs31 = pairs;
  const int2* pairs13 = pairs + (size_t)8 * NCH * PCAP;
  const int* cc31 = cc;
  const int* cc13 = cc + 8 * NCH;

  // ab layout: +0 bn0 (y1), +256 bn1 (y2), +512 bn0_2 (ysc), +768 bn2 (y3)

  // 1: prep (weights transpose + pair lists)
  prep_k<<<36 + 16 * NCH, 256, 0, stream>>>(W1, W12, W2, W3, T1, T12, T2, T3,
                                            nbr31, nbr13, pairs, cc);
  // 2-3: L0+L2 conv (center + off-RMW), stats fused
  center2_k<<<CG, 256, 0, stream>>>(feats, T1, T2, y1, y2, PA, PB);
  off64_k<<<2 * NCH, 256, 0, stream>>>(feats, T1, T2, pairs, cc, y1, y2, PA, PB);
  // 4: bn0, bn1
  fin2_k<<<2, 1024, 0, stream>>>(PA, g0, b0, ab + 0, PB, g1, b1, ab + 256);
  // 5-6: L1 conv: y1 -> ysc (stats into PA)
  c128_k<<<CG, 256, 0, stream>>>(y1, T12, ab + 0, ysc, PA);
  off128_k<<<NCH, 256, 0, stream>>>(y1, T12, pairs13, cc13, ab + 0, ysc, PA);
  // 7-8: L3 conv: y2 -> y3 (=y1, safe now; stats into PB)
  c128_k<<<CG, 256, 0, stream>>>(y2, T3, ab + 256, y3, PB);
  off128_k<<<NCH, 256, 0, stream>>>(y2, T3, pairs31, cc31, ab + 256, y3, PB);
  // 9: bn0_2, bn2
  fin2_k<<<2, 1024, 0, stream>>>(PA, g02, b02, ab + 512, PB, g2, b2, ab + 768);
  // 10: residual add
  final_k<<<12500, 256, 0, stream>>>(y3, ysc, ab + 768, ab + 512, out);
}

// Round 8
// 282.047 us; speedup vs baseline: 2.5906x; 2.5906x over previous
//
#include <hip/hip_runtime.h>

#define NV 200000
#define NCH 391    // chunks of 512 voxels
#define PCAP 56    // pair capacity per (tap, chunk); mean ~14
#define CG 3125    // center blocks (64 rows each)
#define PN 3516    // partial rows per tensor: CG center + NCH off
#define RB1 110    // stage-1 reduction blocks per tensor (32 rows each)

typedef __attribute__((ext_vector_type(8))) short sh8;
typedef __attribute__((ext_vector_type(4))) float f32x4;
typedef __attribute__((ext_vector_type(2))) unsigned int u32x2;

__device__ inline unsigned short f2bf(float f) {
  unsigned int u = __builtin_bit_cast(unsigned int, f);
  u += 0x7FFFu + ((u >> 16) & 1u);
  return (unsigned short)(u >> 16);
}
__device__ inline float bf2f(unsigned short h) {
  unsigned int u = ((unsigned int)h) << 16;
  return __builtin_bit_cast(float, u);
}
__device__ inline float lrelu(float v) { return v >= 0.f ? v : 0.01f * v; }

// ---------------------------------------------------------------------------
// prep: [blocks 0..35] weight transpose W[k][c][d]f32 -> Wt[k][d][c]bf16 via
//       LDS tile. [blocks 36..] pair-list build per (slot, 512-voxel chunk),
//       ballot compaction (deterministic, no atomics, sorted by voxel).
// ---------------------------------------------------------------------------
__global__ __launch_bounds__(256) void prep_k(
    const float* __restrict__ W1, const float* __restrict__ W12,
    const float* __restrict__ W2, const float* __restrict__ W3,
    unsigned short* __restrict__ T1, unsigned short* __restrict__ T12,
    unsigned short* __restrict__ T2, unsigned short* __restrict__ T3,
    const int* __restrict__ nbr31, const int* __restrict__ nbr13,
    int2* __restrict__ pairs, int* __restrict__ cc) {
  __shared__ unsigned short lt[64 * 130];
  __shared__ int base_s[4];
  __shared__ int run;
  int bx = blockIdx.x;
  const int tid = threadIdx.x;
  if (bx < 36) {
    const float* src;
    unsigned short* dst;
    int cin, k;
    if (bx < 9) { src = W1; dst = T1; cin = 64; k = bx; }
    else if (bx < 18) { src = W2; dst = T2; cin = 64; k = bx - 9; }
    else if (bx < 27) { src = W12; dst = T12; cin = 128; k = bx - 18; }
    else { src = W3; dst = T3; cin = 128; k = bx - 27; }
    src += (size_t)k * cin * 128;
    dst += (size_t)k * 128 * cin;
    const int cmask = cin - 1;
    const int csh = (cin == 64) ? 6 : 7;
    for (int h = 0; h < 2; ++h) {  // d-halves [h*64, h*64+64)
      if (h) __syncthreads();
      const int tot = cin * 64;
      for (int e = tid; e < tot; e += 256) {
        const int c = e >> 6, dd = e & 63;
        lt[dd * 130 + c] = f2bf(src[c * 128 + h * 64 + dd]);
      }
      __syncthreads();
      for (int o = tid; o < tot; o += 256) {
        const int dl = o >> csh, c = o & cmask;
        dst[(size_t)(h * 64 + dl) * cin + c] = lt[dl * 130 + c];
      }
    }
    return;
  }
  bx -= 36;
  const int slot = bx / NCH, chunk = bx % NCH;
  const int table = slot >> 3, kk = slot & 7;
  const int k = kk + (kk >= 4);
  const int* nb = (table ? nbr13 : nbr31) + (size_t)k * NV;
  const int lane = tid & 63, wv = tid >> 6;
  if (tid == 0) run = 0;
  __syncthreads();
  int2* pw = pairs + (size_t)(slot * NCH + chunk) * PCAP;
#pragma unroll
  for (int i = 0; i < 2; ++i) {
    const int n = chunk * 512 + i * 256 + tid;
    const int val = (n < NV) ? nb[n] : NV;
    const bool valid = (val != NV);
    const unsigned long long m = __ballot(valid);
    const int loff = __popcll(m & ((1ull << lane) - 1ull));
    if (lane == 0) base_s[wv] = __popcll(m);
    __syncthreads();
    int wbase = run;
    for (int w = 0; w < wv; ++w) wbase += base_s[w];
    if (valid) {
      const int pos = wbase + loff;
      if (pos < PCAP) {
        int2 pr;
        pr.x = val;
        pr.y = n;
        pw[pos] = pr;
      }
    }
    __syncthreads();
    if (tid == 0) run += base_s[0] + base_s[1] + base_s[2] + base_s[3];
    __syncthreads();
  }
  if (tid == 0) cc[slot * NCH + chunk] = min(run, PCAP);
}

// ---------------------------------------------------------------------------
// Epilogue helpers (center kernels): stats shfl-reduce + coalesced tile store.
// ---------------------------------------------------------------------------
#define STATS_EMIT(ACC, PART)                                                   \
  {                                                                             \
    f32x4 ssum[2], ssq[2];                                                      \
    _Pragma("unroll") for (int mt = 0; mt < 2; ++mt) {                          \
      ssum[mt] = (f32x4){0.f, 0.f, 0.f, 0.f};                                   \
      ssq[mt] = (f32x4){0.f, 0.f, 0.f, 0.f};                                    \
      _Pragma("unroll") for (int nt = 0; nt < 4; ++nt)                          \
          _Pragma("unroll") for (int q = 0; q < 4; ++q) {                       \
        const float f = lrelu(ACC[mt][nt][q]);                                  \
        ssum[mt][q] += f;                                                       \
        ssq[mt][q] += f * f;                                                    \
      }                                                                         \
      _Pragma("unroll") for (int off = 1; off < 16; off <<= 1)                  \
          _Pragma("unroll") for (int q = 0; q < 4; ++q) {                       \
        ssum[mt][q] += __shfl_xor(ssum[mt][q], off);                            \
        ssq[mt][q] += __shfl_xor(ssq[mt][q], off);                              \
      }                                                                         \
      if (l15 == 0) {                                                           \
        const int d0 = (wv * 2 + mt) * 16 + l4 * 4;                             \
        *(f32x4*)(PART + (size_t)blockIdx.x * 256 + d0) = ssum[mt];             \
        *(f32x4*)(PART + (size_t)blockIdx.x * 256 + 128 + d0) = ssq[mt];        \
      }                                                                         \
    }                                                                           \
  }

#define TILE_OUT(ACC, YPTR)                                                     \
  {                                                                             \
    __syncthreads();                                                            \
    _Pragma("unroll") for (int mt = 0; mt < 2; ++mt)                            \
        _Pragma("unroll") for (int nt = 0; nt < 4; ++nt) {                      \
      u32x2 pk;                                                                 \
      pk[0] = (unsigned)f2bf(ACC[mt][nt][0]) |                                  \
              ((unsigned)f2bf(ACC[mt][nt][1]) << 16);                           \
      pk[1] = (unsigned)f2bf(ACC[mt][nt][2]) |                                  \
              ((unsigned)f2bf(ACC[mt][nt][3]) << 16);                           \
      *(u32x2*)(&lds[(nt * 16 + l15) * 136 + (wv * 2 + mt) * 16 + l4 * 4]) = pk;\
    }                                                                           \
    __syncthreads();                                                            \
    _Pragma("unroll") for (int j = 0; j < 4; ++j) {                             \
      const int row = j * 16 + (tid >> 4);                                      \
      const int c16 = tid & 15;                                                 \
      const sh8 v = *(const sh8*)(&lds[row * 136 + c16 * 8]);                   \
      *(sh8*)(YPTR + (size_t)(row0 + row) * 128 + c16 * 8) = v;                 \
    }                                                                           \
  }

// ---------------------------------------------------------------------------
// Fused center GEMM for L0+L2: reads feats f32 directly; emits y1,y2 plus
// per-block lrelu stats partials (PA/PB rows [0, CG)).
// ---------------------------------------------------------------------------
__global__ __launch_bounds__(256) void center2_k(
    const float* __restrict__ X, const unsigned short* __restrict__ W1t,
    const unsigned short* __restrict__ W2t, unsigned short* __restrict__ Y1,
    unsigned short* __restrict__ Y2, float* __restrict__ PA,
    float* __restrict__ PB) {
  constexpr int CIN = 64, CH = 8;
  __shared__ unsigned short lds[64 * 136];
  const int tid = threadIdx.x, lane = tid & 63, wv = tid >> 6;
  const int l15 = lane & 15, l4 = lane >> 4;
  const int row0 = blockIdx.x * 64;
  const int js = tid & 7;
#pragma unroll
  for (int i = 0; i < 2; ++i) {
    const int r = (i * 256 + tid) >> 3;
    const f32x4 a = *(const f32x4*)(X + (size_t)(row0 + r) * CIN + js * 8);
    const f32x4 b = *(const f32x4*)(X + (size_t)(row0 + r) * CIN + js * 8 + 4);
    sh8 o;
#pragma unroll
    for (int j = 0; j < 4; ++j) {
      o[j] = (short)f2bf(a[j]);
      o[4 + j] = (short)f2bf(b[j]);
    }
    *(sh8*)(lds + ((size_t)r * CH + (js ^ (r & 7))) * 8) = o;
  }
  __syncthreads();

  f32x4 acc1[2][4], acc2[2][4];
#pragma unroll
  for (int mt = 0; mt < 2; ++mt)
#pragma unroll
    for (int nt = 0; nt < 4; ++nt) {
      acc1[mt][nt] = (f32x4){0.f, 0.f, 0.f, 0.f};
      acc2[mt][nt] = (f32x4){0.f, 0.f, 0.f, 0.f};
    }
  const unsigned short* W1K = W1t + (size_t)(4 * 128) * CIN;
  const unsigned short* W2K = W2t + (size_t)(4 * 128) * CIN;
#pragma unroll
  for (int s = 0; s < 2; ++s) {
    sh8 aw1[2], aw2[2];
#pragma unroll
    for (int mt = 0; mt < 2; ++mt) {
      const int d = (wv * 2 + mt) * 16 + l15;
      aw1[mt] = *(const sh8*)(W1K + (size_t)d * CIN + s * 32 + l4 * 8);
      aw2[mt] = *(const sh8*)(W2K + (size_t)d * CIN + s * 32 + l4 * 8);
    }
#pragma unroll
    for (int nt = 0; nt < 4; ++nt) {
      const int r = nt * 16 + l15;
      const int j = s * 4 + l4;
      const sh8 bx = *(const sh8*)(lds + ((size_t)r * CH + (j ^ (r & 7))) * 8);
#pragma unroll
      for (int mt = 0; mt < 2; ++mt) {
        acc1[mt][nt] =
            __builtin_amdgcn_mfma_f32_16x16x32_bf16(aw1[mt], bx, acc1[mt][nt], 0, 0, 0);
        acc2[mt][nt] =
            __builtin_amdgcn_mfma_f32_16x16x32_bf16(aw2[mt], bx, acc2[mt][nt], 0, 0, 0);
      }
    }
  }
  STATS_EMIT(acc1, PA)
  STATS_EMIT(acc2, PB)
  TILE_OUT(acc1, Y1)
  __syncthreads();
  TILE_OUT(acc2, Y2)
}

// ---------------------------------------------------------------------------
// Center GEMM, CIN=128, affine+lrelu on input; emits Y + stats partials.
// ---------------------------------------------------------------------------
__global__ __launch_bounds__(256) void c128_k(
    const unsigned short* __restrict__ X, const unsigned short* __restrict__ Wt,
    const float* __restrict__ abp, unsigned short* __restrict__ Y,
    float* __restrict__ PART) {
  constexpr int CIN = 128, CH = 16;
  __shared__ unsigned short lds[64 * 136];
  const int row0 = blockIdx.x * 64;
  const int tid = threadIdx.x, lane = tid & 63, wv = tid >> 6;
  const int l15 = lane & 15, l4 = lane >> 4;
  const int js = tid & 15;
  const f32x4 aL = *(const f32x4*)(abp + js * 8);
  const f32x4 aH = *(const f32x4*)(abp + js * 8 + 4);
  const f32x4 bL = *(const f32x4*)(abp + 128 + js * 8);
  const f32x4 bH = *(const f32x4*)(abp + 128 + js * 8 + 4);
#pragma unroll
  for (int i = 0; i < 4; ++i) {
    const int r = (i * 256 + tid) >> 4;
    const sh8 v = *(const sh8*)(X + (size_t)(row0 + r) * CIN + js * 8);
    sh8 o;
#pragma unroll
    for (int j = 0; j < 4; ++j) {
      o[j] = (short)f2bf(lrelu(bf2f((unsigned short)v[j])) * aL[j] + bL[j]);
      o[4 + j] = (short)f2bf(lrelu(bf2f((unsigned short)v[4 + j])) * aH[j] + bH[j]);
    }
    *(sh8*)(lds + ((size_t)r * CH + (js ^ (r & 7))) * 8) = o;
  }
  __syncthreads();

  f32x4 acc[2][4];
#pragma unroll
  for (int mt = 0; mt < 2; ++mt)
#pragma unroll
    for (int nt = 0; nt < 4; ++nt) acc[mt][nt] = (f32x4){0.f, 0.f, 0.f, 0.f};

  const unsigned short* WtK = Wt + (size_t)(4 * 128) * CIN;
#pragma unroll
  for (int s = 0; s < 4; ++s) {
    sh8 aw[2];
#pragma unroll
    for (int mt = 0; mt < 2; ++mt) {
      const int d = (wv * 2 + mt) * 16 + l15;
      aw[mt] = *(const sh8*)(WtK + (size_t)d * CIN + s * 32 + l4 * 8);
    }
#pragma unroll
    for (int nt = 0; nt < 4; ++nt) {
      const int r = nt * 16 + l15;
      const int j = s * 4 + l4;
      const sh8 bxv = *(const sh8*)(lds + ((size_t)r * CH + (j ^ (r & 7))) * 8);
#pragma unroll
      for (int mt = 0; mt < 2; ++mt)
        acc[mt][nt] =
            __builtin_amdgcn_mfma_f32_16x16x32_bf16(aw[mt], bxv, acc[mt][nt], 0, 0, 0);
    }
  }
  STATS_EMIT(acc, PART)
  TILE_OUT(acc, Y)
}

// ---------------------------------------------------------------------------
// Off-center taps for L0+L2 (input feats f32), atomic-free RMW + delta stats.
// grid = 2 layers * NCH; block owns output rows [chunk*512,+512); loops 8 taps.
// ---------------------------------------------------------------------------
__global__ __launch_bounds__(256) void off64_k(
    const float* __restrict__ X, const unsigned short* __restrict__ T1,
    const unsigned short* __restrict__ T2, const int2* __restrict__ pairs,
    const int* __restrict__ cc, unsigned short* __restrict__ y1,
    unsigned short* __restrict__ y2, float* __restrict__ PA,
    float* __restrict__ PB) {
  constexpr int CIN = 64, CH = 8;
  const int layer = blockIdx.x / NCH, chunk = blockIdx.x % NCH;
  const unsigned short* Wt = layer ? T2 : T1;
  unsigned short* Y = layer ? y2 : y1;
  float* PD = layer ? PB : PA;
  const int* ccl = cc + layer * 8 * NCH;
  const int2* pl = pairs + (size_t)layer * 8 * NCH * PCAP;
  __shared__ unsigned short tile[64 * CIN];
  __shared__ int sin[64], sout[64];
  const int tid = threadIdx.x, lane = tid & 63, wv = tid >> 6;
  const int l15 = lane & 15, l4 = lane >> 4;
  const int js = tid & 7;
  f32x4 ds[2], dq[2];
#pragma unroll
  for (int mt = 0; mt < 2; ++mt) {
    ds[mt] = (f32x4){0.f, 0.f, 0.f, 0.f};
    dq[mt] = (f32x4){0.f, 0.f, 0.f, 0.f};
  }

  for (int kk = 0; kk < 8; ++kk) {
    const int n0 = ccl[kk * NCH + chunk];
    if (n0 == 0) continue;
    const int k = kk + (kk >= 4);
    const unsigned short* WtK = Wt + (size_t)k * 128 * CIN;
    __syncthreads();
    if (tid < 64) {
      int2 pr;
      if (tid < n0) pr = pl[(size_t)(kk * NCH + chunk) * PCAP + tid];
      else { pr.x = NV; pr.y = NV; }
      sin[tid] = pr.x;
      sout[tid] = pr.y;
    }
    __syncthreads();
#pragma unroll
    for (int i = 0; i < 2; ++i) {
      const int r = (i * 256 + tid) >> 3;
      const int in = sin[r];
      sh8 o = (sh8){0, 0, 0, 0, 0, 0, 0, 0};
      if (in != NV) {
        const f32x4 a = *(const f32x4*)(X + (size_t)in * CIN + js * 8);
        const f32x4 b = *(const f32x4*)(X + (size_t)in * CIN + js * 8 + 4);
#pragma unroll
        for (int j = 0; j < 4; ++j) {
          o[j] = (short)f2bf(a[j]);
          o[4 + j] = (short)f2bf(b[j]);
        }
      }
      *(sh8*)(tile + ((size_t)r * CH + (js ^ (r & 7))) * 8) = o;
    }
    __syncthreads();

    f32x4 acc[2][4];
#pragma unroll
    for (int mt = 0; mt < 2; ++mt)
#pragma unroll
      for (int nt = 0; nt < 4; ++nt) acc[mt][nt] = (f32x4){0.f, 0.f, 0.f, 0.f};
#pragma unroll
    for (int s = 0; s < 2; ++s) {
      sh8 aw[2];
#pragma unroll
      for (int mt = 0; mt < 2; ++mt) {
        const int d = (wv * 2 + mt) * 16 + l15;
        aw[mt] = *(const sh8*)(WtK + (size_t)d * CIN + s * 32 + l4 * 8);
      }
#pragma unroll
      for (int nt = 0; nt < 4; ++nt) {
        const int r = nt * 16 + l15;
        const int j = s * 4 + l4;
        const sh8 bxv = *(const sh8*)(tile + ((size_t)r * CH + (j ^ (r & 7))) * 8);
#pragma unroll
        for (int mt = 0; mt < 2; ++mt)
          acc[mt][nt] =
              __builtin_amdgcn_mfma_f32_16x16x32_bf16(aw[mt], bxv, acc[mt][nt], 0, 0, 0);
      }
    }
#pragma unroll
    for (int mt = 0; mt < 2; ++mt)
#pragma unroll
      for (int nt = 0; nt < 4; ++nt) {
        const int out = sout[nt * 16 + l15];
        if (out == NV) continue;
        const int d0 = (wv * 2 + mt) * 16 + l4 * 4;
        unsigned short* p = Y + (size_t)out * 128 + d0;
        const u32x2 old = *(const u32x2*)p;
        u32x2 nw;
        float of[4], sf[4];
        of[0] = bf2f((unsigned short)(old[0] & 0xffff));
        of[1] = bf2f((unsigned short)(old[0] >> 16));
        of[2] = bf2f((unsigned short)(old[1] & 0xffff));
        of[3] = bf2f((unsigned short)(old[1] >> 16));
#pragma unroll
        for (int q = 0; q < 4; ++q) {
          sf[q] = of[q] + acc[mt][nt][q];
          const float ln = lrelu(sf[q]), lo = lrelu(of[q]);
          ds[mt][q] += ln - lo;
          dq[mt][q] += ln * ln - lo * lo;
        }
        nw[0] = (unsigned)f2bf(sf[0]) | ((unsigned)f2bf(sf[1]) << 16);
        nw[1] = (unsigned)f2bf(sf[2]) | ((unsigned)f2bf(sf[3]) << 16);
        *(u32x2*)p = nw;
      }
  }
#pragma unroll
  for (int mt = 0; mt < 2; ++mt) {
#pragma unroll
    for (int off = 1; off < 16; off <<= 1)
#pragma unroll
      for (int q = 0; q < 4; ++q) {
        ds[mt][q] += __shfl_xor(ds[mt][q], off);
        dq[mt][q] += __shfl_xor(dq[mt][q], off);
      }
    if (l15 == 0) {
      const int d0 = (wv * 2 + mt) * 16 + l4 * 4;
      *(f32x4*)(PD + (size_t)(CG + chunk) * 256 + d0) = ds[mt];
      *(f32x4*)(PD + (size_t)(CG + chunk) * 256 + 128 + d0) = dq[mt];
    }
  }
}

// ---------------------------------------------------------------------------
// Off-center taps, CIN=128, one table, RMW + delta stats. grid = NCH.
// ---------------------------------------------------------------------------
__global__ __launch_bounds__(256) void off128_k(
    const unsigned short* __restrict__ X, const unsigned short* __restrict__ Wt,
    const int2* __restrict__ pairs_t, const int* __restrict__ cc_t,
    const float* __restrict__ abp, unsigned short* __restrict__ Y,
    float* __restrict__ PD) {
  constexpr int CIN = 128, CH = 16;
  const int chunk = blockIdx.x;
  __shared__ unsigned short tile[64 * CIN];
  __shared__ int sin[64], sout[64];
  const int tid = threadIdx.x, lane = tid & 63, wv = tid >> 6;
  const int l15 = lane & 15, l4 = lane >> 4;
  const int js = tid & 15;
  const f32x4 aL = *(const f32x4*)(abp + js * 8);
  const f32x4 aH = *(const f32x4*)(abp + js * 8 + 4);
  const f32x4 bL = *(const f32x4*)(abp + 128 + js * 8);
  const f32x4 bH = *(const f32x4*)(abp + 128 + js * 8 + 4);
  f32x4 ds[2], dq[2];
#pragma unroll
  for (int mt = 0; mt < 2; ++mt) {
    ds[mt] = (f32x4){0.f, 0.f, 0.f, 0.f};
    dq[mt] = (f32x4){0.f, 0.f, 0.f, 0.f};
  }

  for (int kk = 0; kk < 8; ++kk) {
    const int n0 = cc_t[kk * NCH + chunk];
    if (n0 == 0) continue;
    const int k = kk + (kk >= 4);
    const unsigned short* WtK = Wt + (size_t)k * 128 * CIN;
    __syncthreads();
    if (tid < 64) {
      int2 pr;
      if (tid < n0) pr = pairs_t[(size_t)(kk * NCH + chunk) * PCAP + tid];
      else { pr.x = NV; pr.y = NV; }
      sin[tid] = pr.x;
      sout[tid] = pr.y;
    }
    __syncthreads();
#pragma unroll
    for (int i = 0; i < 4; ++i) {
      const int r = (i * 256 + tid) >> 4;
      const int in = sin[r];
      sh8 o = (sh8){0, 0, 0, 0, 0, 0, 0, 0};
      if (in != NV) {
        const sh8 v = *(const sh8*)(X + (size_t)in * CIN + js * 8);
#pragma unroll
        for (int j = 0; j < 4; ++j) {
          o[j] = (short)f2bf(lrelu(bf2f((unsigned short)v[j])) * aL[j] + bL[j]);
          o[4 + j] = (short)f2bf(lrelu(bf2f((unsigned short)v[4 + j])) * aH[j] + bH[j]);
        }
      }
      *(sh8*)(tile + ((size_t)r * CH + (js ^ (r & 7))) * 8) = o;
    }
    __syncthreads();

    f32x4 acc[2][4];
#pragma unroll
    for (int mt = 0; mt < 2; ++mt)
#pragma unroll
      for (int nt = 0; nt < 4; ++nt) acc[mt][nt] = (f32x4){0.f, 0.f, 0.f, 0.f};
#pragma unroll
    for (int s = 0; s < 4; ++s) {
      sh8 aw[2];
#pragma unroll
      for (int mt = 0; mt < 2; ++mt) {
        const int d = (wv * 2 + mt) * 16 + l15;
        aw[mt] = *(const sh8*)(WtK + (size_t)d * CIN + s * 32 + l4 * 8);
      }
#pragma unroll
      for (int nt = 0; nt < 4; ++nt) {
        const int r = nt * 16 + l15;
        const int j = s * 4 + l4;
        const sh8 bxv = *(const sh8*)(tile + ((size_t)r * CH + (j ^ (r & 7))) * 8);
#pragma unroll
        for (int mt = 0; mt < 2; ++mt)
          acc[mt][nt] =
              __builtin_amdgcn_mfma_f32_16x16x32_bf16(aw[mt], bxv, acc[mt][nt], 0, 0, 0);
      }
    }
#pragma unroll
    for (int mt = 0; mt < 2; ++mt)
#pragma unroll
      for (int nt = 0; nt < 4; ++nt) {
        const int out = sout[nt * 16 + l15];
        if (out == NV) continue;
        const int d0 = (wv * 2 + mt) * 16 + l4 * 4;
        unsigned short* p = Y + (size_t)out * 128 + d0;
        const u32x2 old = *(const u32x2*)p;
        u32x2 nw;
        float of[4], sf[4];
        of[0] = bf2f((unsigned short)(old[0] & 0xffff));
        of[1] = bf2f((unsigned short)(old[0] >> 16));
        of[2] = bf2f((unsigned short)(old[1] & 0xffff));
        of[3] = bf2f((unsigned short)(old[1] >> 16));
#pragma unroll
        for (int q = 0; q < 4; ++q) {
          sf[q] = of[q] + acc[mt][nt][q];
          const float ln = lrelu(sf[q]), lo = lrelu(of[q]);
          ds[mt][q] += ln - lo;
          dq[mt][q] += ln * ln - lo * lo;
        }
        nw[0] = (unsigned)f2bf(sf[0]) | ((unsigned)f2bf(sf[1]) << 16);
        nw[1] = (unsigned)f2bf(sf[2]) | ((unsigned)f2bf(sf[3]) << 16);
        *(u32x2*)p = nw;
      }
  }
#pragma unroll
  for (int mt = 0; mt < 2; ++mt) {
#pragma unroll
    for (int off = 1; off < 16; off <<= 1)
#pragma unroll
      for (int q = 0; q < 4; ++q) {
        ds[mt][q] += __shfl_xor(ds[mt][q], off);
        dq[mt][q] += __shfl_xor(dq[mt][q], off);
      }
    if (l15 == 0) {
      const int d0 = (wv * 2 + mt) * 16 + l4 * 4;
      *(f32x4*)(PD + (size_t)(CG + chunk) * 256 + d0) = ds[mt];
      *(f32x4*)(PD + (size_t)(CG + chunk) * 256 + 128 + d0) = dq[mt];
    }
  }
}

// ---------------------------------------------------------------------------
// Stage-1 partial reduction: 2*RB1 blocks; block sums 32 partial rows.
// ---------------------------------------------------------------------------
__global__ __launch_bounds__(256) void red1_k(const float* __restrict__ PA,
                                              const float* __restrict__ PB,
                                              float* __restrict__ RA,
                                              float* __restrict__ RB) {
  const int tb = blockIdx.x / RB1;
  const int b = blockIdx.x % RB1;
  const float* P = tb ? PB : PA;
  float* R = tb ? RB : RA;
  const int c = threadIdx.x;
  const int r0 = b * 32;
  const int r1 = (r0 + 32 < PN) ? r0 + 32 : PN;
  float s = 0.f;
#pragma unroll 4
  for (int r = r0; r < r1; ++r) s += P[(size_t)r * 256 + c];
  R[(size_t)b * 256 + c] = s;
}

// ---------------------------------------------------------------------------
// Reduce RB1 reduced rows -> per-channel scale/bias. 2 blocks x 1024 threads.
// ---------------------------------------------------------------------------
__global__ __launch_bounds__(1024) void fin2_k(
    const float* __restrict__ RA, const float* __restrict__ gA,
    const float* __restrict__ btA, float* __restrict__ abA,
    const float* __restrict__ RB, const float* __restrict__ gB,
    const float* __restrict__ btB, float* __restrict__ abB) {
  const float* R = blockIdx.x ? RB : RA;
  const float* g = blockIdx.x ? gB : gA;
  const float* bt = blockIdx.x ? btB : btA;
  float* abo = blockIdx.x ? abB : abA;
  __shared__ float S[1024];
  const int t = threadIdx.x;
  const int c = t & 255, grp = t >> 8;
  float s = 0.f;
  for (int b = grp; b < RB1; b += 4) s += R[(size_t)b * 256 + c];
  S[t] = s;
  __syncthreads();
  if (t < 256) S[t] = S[t] + S[256 + t] + S[512 + t] + S[768 + t];
  __syncthreads();
  if (t < 128) {
    const float m = S[t] * (1.0f / (float)NV);
    const float v = S[128 + t] * (1.0f / (float)NV) - m * m;
    const float a = g[t] * rsqrtf(v + 1e-5f);
    abo[t] = a;
    abo[128 + t] = bt[t] - m * a;
  }
}

// ---------------------------------------------------------------------------
// out = bn2(lrelu(y3)) + bn0_2(lrelu(ysc))   (f32 output)
// ---------------------------------------------------------------------------
__global__ __launch_bounds__(256) void final_k(const unsigned short* __restrict__ y3,
                                               const unsigned short* __restrict__ ysc,
                                               const float* __restrict__ ab3,
                                               const float* __restrict__ ab1,
                                               float* __restrict__ out) {
  const long i = (long)blockIdx.x * 256 + threadIdx.x;
  if (i >= (long)NV * 16) return;
  const long base = i * 8;
  const int c0 = (int)(base & 127);
  const sh8 v3 = *(const sh8*)(y3 + base);
  const sh8 vs = *(const sh8*)(ysc + base);
  const f32x4 a3L = *(const f32x4*)(ab3 + c0);
  const f32x4 a3H = *(const f32x4*)(ab3 + c0 + 4);
  const f32x4 b3L = *(const f32x4*)(ab3 + 128 + c0);
  const f32x4 b3H = *(const f32x4*)(ab3 + 128 + c0 + 4);
  const f32x4 a1L = *(const f32x4*)(ab1 + c0);
  const f32x4 a1H = *(const f32x4*)(ab1 + c0 + 4);
  const f32x4 b1L = *(const f32x4*)(ab1 + 128 + c0);
  const f32x4 b1H = *(const f32x4*)(ab1 + 128 + c0 + 4);
  f32x4 oL, oH;
#pragma unroll
  for (int j = 0; j < 4; ++j) {
    oL[j] = a3L[j] * lrelu(bf2f((unsigned short)v3[j])) + b3L[j] +
            a1L[j] * lrelu(bf2f((unsigned short)vs[j])) + b1L[j];
    oH[j] = a3H[j] * lrelu(bf2f((unsigned short)v3[4 + j])) + b3H[j] +
            a1H[j] * lrelu(bf2f((unsigned short)vs[4 + j])) + b1H[j];
  }
  *(f32x4*)(out + base) = oL;
  *(f32x4*)(out + base + 4) = oH;
}

// ---------------------------------------------------------------------------
extern "C" void kernel_launch(void* const* d_in, const int* in_sizes, int n_in,
                              void* d_out, int out_size, void* d_ws, size_t ws_size,
                              hipStream_t stream) {
  const float* feats = (const float*)d_in[0];
  const float* W1 = (const float*)d_in[1];
  const float* W12 = (const float*)d_in[2];
  const float* W2 = (const float*)d_in[3];
  const float* W3 = (const float*)d_in[4];
  const float* g0 = (const float*)d_in[5];
  const float* b0 = (const float*)d_in[6];
  const float* g02 = (const float*)d_in[7];
  const float* b02 = (const float*)d_in[8];
  const float* g1 = (const float*)d_in[9];
  const float* b1 = (const float*)d_in[10];
  const float* g2 = (const float*)d_in[11];
  const float* b2 = (const float*)d_in[12];
  const int* nbr31 = (const int*)d_in[13];
  const int* nbr13 = (const int*)d_in[14];
  float* out = (float*)d_out;

  char* ws = (char*)d_ws;
  size_t off = 0;
  auto alloc = [&](size_t bytes) {
    char* p = ws + off;
    off = (off + bytes + 255) & ~(size_t)255;
    return p;
  };

  unsigned short* T1 = (unsigned short*)alloc((size_t)9 * 128 * 64 * 2);
  unsigned short* T2 = (unsigned short*)alloc((size_t)9 * 128 * 64 * 2);
  unsigned short* T12 = (unsigned short*)alloc((size_t)9 * 128 * 128 * 2);
  unsigned short* T3 = (unsigned short*)alloc((size_t)9 * 128 * 128 * 2);
  unsigned short* y1 = (unsigned short*)alloc((size_t)NV * 128 * 2);
  unsigned short* ysc = (unsigned short*)alloc((size_t)NV * 128 * 2);
  unsigned short* y2 = (unsigned short*)alloc((size_t)NV * 128 * 2);
  float* PA = (float*)alloc((size_t)PN * 256 * 4);
  float* PB = (float*)alloc((size_t)PN * 256 * 4);
  float* RA = (float*)alloc((size_t)RB1 * 256 * 4);
  float* RB = (float*)alloc((size_t)RB1 * 256 * 4);
  float* ab = (float*)alloc(1024 * 4);
  int* cc = (int*)alloc((size_t)16 * NCH * 4);
  int2* pairs = (int2*)alloc((size_t)16 * NCH * PCAP * 8);
  unsigned short* y3 = y1;  // y1 reused as y3 only after all y1 readers drain

  const int2* pairs31 = pairs;
  const int2* pairs13 = pairs + (size_t)8 * NCH * PCAP;
  const int* cc31 = cc;
  const int* cc13 = cc + 8 * NCH;

  // ab layout: +0 bn0 (y1), +256 bn1 (y2), +512 bn0_2 (ysc), +768 bn2 (y3)

  // 1: prep (weights transpose + pair lists)
  prep_k<<<36 + 16 * NCH, 256, 0, stream>>>(W1, W12, W2, W3, T1, T12, T2, T3,
                                            nbr31, nbr13, pairs, cc);
  // 2-3: L0+L2 conv (center + off-RMW), stats fused
  center2_k<<<CG, 256, 0, stream>>>(feats, T1, T2, y1, y2, PA, PB);
  off64_k<<<2 * NCH, 256, 0, stream>>>(feats, T1, T2, pairs, cc, y1, y2, PA, PB);
  // 4-5: bn0, bn1 (two-stage reduction)
  red1_k<<<2 * RB1, 256, 0, stream>>>(PA, PB, RA, RB);
  fin2_k<<<2, 1024, 0, stream>>>(RA, g0, b0, ab + 0, RB, g1, b1, ab + 256);
  // 6-7: L1 conv: y1 -> ysc (stats into PA)
  c128_k<<<CG, 256, 0, stream>>>(y1, T12, ab + 0, ysc, PA);
  off128_k<<<NCH, 256, 0, stream>>>(y1, T12, pairs13, cc13, ab + 0, ysc, PA);
  // 8-9: L3 conv: y2 -> y3 (=y1, safe now; stats into PB)
  c128_k<<<CG, 256, 0, stream>>>(y2, T3, ab + 256, y3, PB);
  off128_k<<<NCH, 256, 0, stream>>>(y2, T3, pairs31, cc31, ab + 256, y3, PB);
  // 10-11: bn0_2, bn2
  red1_k<<<2 * RB1, 256, 0, stream>>>(PA, PB, RA, RB);
  fin2_k<<<2, 1024, 0, stream>>>(RA, g02, b02, ab + 512, RB, g2, b2, ab + 768);
  // 12: residual add
  final_k<<<12500, 256, 0, stream>>>(y3, ysc, ab + 768, ab + 512, out);
}